// Round 3
// baseline (241.994 us; speedup 1.0000x reference)
//
#include <hip/hip_runtime.h>

#define NN 4096
#define DD 512
#define HH 8
#define FF 64
#define LRELU_ALPHA 0.2f
#define SP 72   // LDS row stride in bf16 elems
#define JSPLIT 2
#define JCHUNK (NN / JSPLIT)

typedef __attribute__((ext_vector_type(8))) short bf16x8;
typedef __attribute__((ext_vector_type(4))) float f32x4;

__device__ __forceinline__ float f4c(const float4& v, int k) {
    return k == 0 ? v.x : (k == 1 ? v.y : (k == 2 ? v.z : v.w));
}
__device__ __forceinline__ void f4s(float4& v, int k, float x) {
    if (k == 0) v.x = x; else if (k == 1) v.y = x; else if (k == 2) v.z = x; else v.w = x;
}
__device__ __forceinline__ unsigned short f2bf(float x) {   // RNE float->bf16
    unsigned u = __float_as_uint(x);
    return (unsigned short)((u + 0x7fffu + ((u >> 16) & 1u)) >> 16);
}
__device__ __forceinline__ float bf2f(unsigned short h) {
    return __uint_as_float(((unsigned)h) << 16);
}
// monotone float<->uint key for atomicMax on arbitrary-sign floats
__device__ __forceinline__ unsigned fkey(float x) {
    unsigned u = __float_as_uint(x);
    return (u & 0x80000000u) ? ~u : (u | 0x80000000u);
}
__device__ __forceinline__ float funkey(unsigned k) {
    unsigned u = (k & 0x80000000u) ? (k ^ 0x80000000u) : ~k;
    return __uint_as_float(u);
}

// ================= Kernel 1: fused prep =================
// [0,1024)     : adjacency -> lane-indexed 64-bit MFMA masks adjm[g][t][16]
//                bit l of adjm[g][t][k2*8+e] = adj[16g + (l&15)][64t + 32k2 + 8*(l>>4) + e]
// [1024,1088)  : split+transpose W -> wt_hi/wt_lo [h][f][d]
// 1088         : zero mxkey + hpsum
// [1089,1609)  : zero oacc+oli (2,129,920 floats)
__global__ __launch_bounds__(256) void k_prep(const int* __restrict__ adj,
                                              const float* __restrict__ W,
                                              unsigned long long* __restrict__ adjm,
                                              unsigned short* __restrict__ wt_hi,
                                              unsigned short* __restrict__ wt_lo,
                                              unsigned* __restrict__ mxkey,
                                              float* __restrict__ hpsum,
                                              float* __restrict__ oacc) {
    __shared__ unsigned long long shbuf[2080];   // 16640 B, aliased per branch
    int b = blockIdx.x, t = threadIdx.x;
    if (b < 1024) {
        int g = b >> 2, cq = b & 3;
        int r0 = g * 16;
        int lane = t & 63, wv = t >> 6;
        unsigned long long (*w64)[17] = (unsigned long long(*)[17])shbuf;
        // phase 1: coalesced row-pack of 16 rows x 1024 cols into LDS words
        for (int r = 0; r < 16; r++) {
            #pragma unroll
            for (int q = 0; q < 4; q++) {
                int col = cq * 1024 + q * 256 + t;
                unsigned long long m = __ballot(adj[(size_t)(r0 + r) * NN + col] > 0);
                if (lane == 0) w64[r][q * 4 + wv] = m;
            }
        }
        __syncthreads();
        // phase 2: transpose-repack into lane-indexed MFMA masks via ballot
        for (int tt = wv; tt < 16; tt += 4) {
            unsigned long long wbits = w64[lane & 15][tt];
            unsigned long long my = 0;
            #pragma unroll
            for (int k = 0; k < 16; k++) {
                int shv = 32 * (k >> 3) + 8 * (lane >> 4) + (k & 7);
                unsigned long long bal = __ballot((unsigned)((wbits >> shv) & 1ULL));
                if (lane == k) my = bal;
            }
            if (lane < 16)
                adjm[((size_t)g * 64 + cq * 16 + tt) * 16 + lane] = my;
        }
    } else if (b < 1088) {
        float (*tile)[65] = (float(*)[65])shbuf;
        int idx = b - 1024;
        int h = idx >> 3;
        int d0 = (idx & 7) * 64;
        #pragma unroll
        for (int kidx = 0; kidx < 4; kidx++) {
            int id = t + 256 * kidx;
            int dd = id >> 4, f4i = (id & 15) * 4;
            float4 v = *(const float4*)(W + ((size_t)(h * DD + d0 + dd)) * FF + f4i);
            tile[dd][f4i] = v.x; tile[dd][f4i + 1] = v.y;
            tile[dd][f4i + 2] = v.z; tile[dd][f4i + 3] = v.w;
        }
        __syncthreads();
        int f = t >> 2, c = (t & 3) * 16;
        union { unsigned short s[16]; uint4 v[2]; } hb, lb;
        #pragma unroll
        for (int q = 0; q < 16; q++) {
            float v = tile[c + q][f];
            unsigned short hi = f2bf(v);
            hb.s[q] = hi;
            lb.s[q] = f2bf(v - bf2f(hi));
        }
        uint4* dh = (uint4*)(wt_hi + ((size_t)h * FF + f) * DD + d0 + c);
        uint4* dl = (uint4*)(wt_lo + ((size_t)h * FF + f) * DD + d0 + c);
        dh[0] = hb.v[0]; dh[1] = hb.v[1];
        dl[0] = lb.v[0]; dl[1] = lb.v[1];
    } else if (b == 1088) {
        if (t < 16) mxkey[t] = 0u;
        hpsum[t] = 0.f;
        hpsum[t + 256] = 0.f;
    } else {
        int z = b - 1089;                       // [0,520): zero oacc (2,097,152) + oli (32,768)
        float4 zv = make_float4(0.f, 0.f, 0.f, 0.f);
        float4* zp = (float4*)oacc;
        #pragma unroll
        for (int q = 0; q < 4; q++)
            zp[(size_t)z * 1024 + q * 256 + t] = zv;
    }
}

// ================= Kernel 2: hp GEMM (inline fp32->hi/lo split of h; MFMA 3-product) ========
// Emits hpT_hi, fs/fd (PRE-SCALED by LOG2E), maxfd atomic on scaled fd, hpsum column-sum.
__global__ __launch_bounds__(256) void k_hp_mfma(const float* __restrict__ hmat,
                                                 const unsigned short* __restrict__ whi,
                                                 const unsigned short* __restrict__ wlo,
                                                 const float* __restrict__ a,
                                                 unsigned short* __restrict__ hpT_hi,
                                                 float* __restrict__ fs,
                                                 float* __restrict__ fd,
                                                 float* __restrict__ hpsum,
                                                 unsigned* __restrict__ mxkey) {
    __shared__ char smem[4 * 64 * SP * 2];   // 36864 B
    unsigned short* ah = (unsigned short*)smem;
    unsigned short* al = ah + 64 * SP;
    unsigned short* bh = al + 64 * SP;
    unsigned short* bl = bh + 64 * SP;

    int t = threadIdx.x;
    int h = blockIdx.y;
    int n0 = blockIdx.x * 64;
    int lane = t & 63;
    int w = t >> 6;
    int R0 = (w >> 1) * 32, F0 = (w & 1) * 32;
    int am = lane & 15, aq = lane >> 4;
    int sr = t >> 2, sc = (t & 3) * 16;

    const float* gha = hmat + (size_t)(n0 + sr) * DD;
    const unsigned short* gbh = whi + ((size_t)h * FF + sr) * DD;
    const unsigned short* gbl = wlo + ((size_t)h * FF + sr) * DD;

    f32x4 acc[2][2] = {};
    for (int kk = 0; kk < DD; kk += 64) {
        {   // h: fp32 load + inline hi/lo split
            float4 p0 = *(const float4*)(gha + kk + sc);
            float4 p1 = *(const float4*)(gha + kk + sc + 4);
            float4 p2 = *(const float4*)(gha + kk + sc + 8);
            float4 p3 = *(const float4*)(gha + kk + sc + 12);
            union { unsigned short s[16]; uint4 v[2]; } hb, lb;
            #pragma unroll
            for (int q = 0; q < 16; q++) {
                float v = q < 4 ? f4c(p0, q) : q < 8 ? f4c(p1, q - 4)
                          : q < 12 ? f4c(p2, q - 8) : f4c(p3, q - 12);
                unsigned short hi = f2bf(v);
                hb.s[q] = hi;
                lb.s[q] = f2bf(v - bf2f(hi));
            }
            *(uint4*)(ah + sr * SP + sc) = hb.v[0]; *(uint4*)(ah + sr * SP + sc + 8) = hb.v[1];
            *(uint4*)(al + sr * SP + sc) = lb.v[0]; *(uint4*)(al + sr * SP + sc + 8) = lb.v[1];
        }
        {
            const uint4* s2 = (const uint4*)(gbh + kk + sc);
            const uint4* s3 = (const uint4*)(gbl + kk + sc);
            uint4 w0 = s2[0], w1 = s2[1], x0 = s3[0], x1 = s3[1];
            *(uint4*)(bh + sr * SP + sc) = w0; *(uint4*)(bh + sr * SP + sc + 8) = w1;
            *(uint4*)(bl + sr * SP + sc) = x0; *(uint4*)(bl + sr * SP + sc + 8) = x1;
        }
        __syncthreads();
        #pragma unroll
        for (int k2 = 0; k2 < 2; k2++) {
            int ko = k2 * 32 + aq * 8;
            bf16x8 a0h = *(const bf16x8*)(ah + (R0 + am) * SP + ko);
            bf16x8 a1h = *(const bf16x8*)(ah + (R0 + 16 + am) * SP + ko);
            bf16x8 a0l = *(const bf16x8*)(al + (R0 + am) * SP + ko);
            bf16x8 a1l = *(const bf16x8*)(al + (R0 + 16 + am) * SP + ko);
            bf16x8 b0h = *(const bf16x8*)(bh + (F0 + am) * SP + ko);
            bf16x8 b1h = *(const bf16x8*)(bh + (F0 + 16 + am) * SP + ko);
            bf16x8 b0l = *(const bf16x8*)(bl + (F0 + am) * SP + ko);
            bf16x8 b1l = *(const bf16x8*)(bl + (F0 + 16 + am) * SP + ko);
            acc[0][0] = __builtin_amdgcn_mfma_f32_16x16x32_bf16(a0h, b0h, acc[0][0], 0, 0, 0);
            acc[0][1] = __builtin_amdgcn_mfma_f32_16x16x32_bf16(a0h, b1h, acc[0][1], 0, 0, 0);
            acc[1][0] = __builtin_amdgcn_mfma_f32_16x16x32_bf16(a1h, b0h, acc[1][0], 0, 0, 0);
            acc[1][1] = __builtin_amdgcn_mfma_f32_16x16x32_bf16(a1h, b1h, acc[1][1], 0, 0, 0);
            acc[0][0] = __builtin_amdgcn_mfma_f32_16x16x32_bf16(a0h, b0l, acc[0][0], 0, 0, 0);
            acc[0][1] = __builtin_amdgcn_mfma_f32_16x16x32_bf16(a0h, b1l, acc[0][1], 0, 0, 0);
            acc[1][0] = __builtin_amdgcn_mfma_f32_16x16x32_bf16(a1h, b0l, acc[1][0], 0, 0, 0);
            acc[1][1] = __builtin_amdgcn_mfma_f32_16x16x32_bf16(a1h, b1l, acc[1][1], 0, 0, 0);
            acc[0][0] = __builtin_amdgcn_mfma_f32_16x16x32_bf16(a0l, b0h, acc[0][0], 0, 0, 0);
            acc[0][1] = __builtin_amdgcn_mfma_f32_16x16x32_bf16(a0l, b1h, acc[0][1], 0, 0, 0);
            acc[1][0] = __builtin_amdgcn_mfma_f32_16x16x32_bf16(a1l, b0h, acc[1][0], 0, 0, 0);
            acc[1][1] = __builtin_amdgcn_mfma_f32_16x16x32_bf16(a1l, b1h, acc[1][1], 0, 0, 0);
        }
        __syncthreads();
    }

    // Epilogue: pack hi/lo to LDS [f][n], store hi, fs/fd (scaled by LOG2E), maxfd, hpsum.
    unsigned* tt = (unsigned*)smem;
    float* rs = (float*)(smem + 17408);
    float* rd = rs + 256;
    float* ash = rd + 256;
    if (t < 128) ash[t] = a[h * 2 * FF + t];
    int col = lane & 15, rbase = (lane >> 4) * 4;
    #pragma unroll
    for (int m16 = 0; m16 < 2; m16++) {
        #pragma unroll
        for (int n16 = 0; n16 < 2; n16++) {
            #pragma unroll
            for (int r = 0; r < 4; r++) {
                int nl = R0 + m16 * 16 + rbase + r;
                int f = F0 + n16 * 16 + col;
                float v = acc[m16][n16][r];
                unsigned short hi = f2bf(v);
                unsigned short lo = f2bf(v - bf2f(hi));
                tt[f * 68 + nl] = (unsigned)hi | ((unsigned)lo << 16);
            }
        }
    }
    __syncthreads();
    {
        int f = t >> 2, c = (t & 3) * 16;
        union { unsigned short s[16]; uint4 v[2]; } hb;
        float csum = 0.f;
        #pragma unroll
        for (int q = 0; q < 16; q++) {
            unsigned u = tt[f * 68 + c + q];
            hb.s[q] = (unsigned short)(u & 0xffffu);
            csum += bf2f((unsigned short)(u & 0xffffu)) + bf2f((unsigned short)(u >> 16));
        }
        uint4* dh = (uint4*)(hpT_hi + ((size_t)h * FF + f) * NN + n0 + c);
        dh[0] = hb.v[0]; dh[1] = hb.v[1];
        csum += __shfl_xor(csum, 1);
        csum += __shfl_xor(csum, 2);
        if ((t & 3) == 0) unsafeAtomicAdd(hpsum + h * FF + f, csum);
    }
    {
        int n = t & 63, g = t >> 6;
        float fsp = 0.f, fdp = 0.f;
        #pragma unroll
        for (int q = 0; q < 16; q++) {
            int f = g * 16 + q;
            unsigned u = tt[f * 68 + n];
            float v = bf2f((unsigned short)(u & 0xffffu)) + bf2f((unsigned short)(u >> 16));
            fsp += v * ash[f];
            fdp += v * ash[64 + f];
        }
        rs[g * 64 + n] = fsp;
        rd[g * 64 + n] = fdp;
    }
    __syncthreads();
    if (t < 64) {
        const float LOG2E = 1.44269504f;
        float fdv = (rd[t] + rd[64 + t] + rd[128 + t] + rd[192 + t]) * LOG2E;
        fs[(size_t)h * NN + n0 + t] = (rs[t] + rs[64 + t] + rs[128 + t] + rs[192 + t]) * LOG2E;
        fd[(size_t)h * NN + n0 + t] = fdv;
        unsigned key = fkey(fdv);
        #pragma unroll
        for (int off = 32; off; off >>= 1) key = max(key, (unsigned)__shfl_xor((int)key, off));
        if (t == 0) atomicMax(mxkey + h, key);
    }
}

// ================= Kernel 3: attention — verified round-1 body + j-split partials ==========
// grid (NN/64, HH, JSPLIT), 256 threads = 4 waves; wave w owns i-rows [i0+16w, +16).
// Each part-block runs the IDENTICAL double-buffered loop over JCHUNK columns and
// atomically accumulates partial acc (f32) and row-sum li into zeroed workspace.
__global__ __launch_bounds__(256) void k_attn(const float* __restrict__ fs,
                                              const float* __restrict__ fd,
                                              const unsigned* __restrict__ mxkey,
                                              const unsigned long long* __restrict__ adjm,
                                              const unsigned short* __restrict__ hpT_hi,
                                              float* __restrict__ oacc,
                                              float* __restrict__ oli) {
    __shared__ unsigned short hbh[2][64 * SP];

    int t = threadIdx.x;
    int h = blockIdx.y;
    int i0 = blockIdx.x * 64;
    int jlo = blockIdx.z * JCHUNK;
    int lane = t & 63;
    int w = t >> 6;
    int am = lane & 15, aq = lane >> 4;
    int sr = t >> 2, sc = (t & 3) * 16;   // hp staging: f-row, j-chunk

    // per-row constants (scaled domain): arg = max(tv, 0.2*tv + Ci), tv = Ai + fdL_j
    float mfdL = funkey(mxkey[h]);
    float fsv = fs[(size_t)h * NN + i0 + w * 16 + am];
    float sL = fsv + mfdL;
    float mrL = fmaxf(sL, LRELU_ALPHA * sL);
    float Ai = fsv - mrL;
    float Ci = -0.8f * mrL;

    int wu = __builtin_amdgcn_readfirstlane(w);
    const unsigned long long* mbase = adjm + ((size_t)(blockIdx.x * 4 + wu) * 64) * 16;
    const unsigned short* gH = hpT_hi + (size_t)h * FF * NN;
    const float* fdh = fd + (size_t)h * NN;

    f32x4 acc[4] = {};
    f32x4 accl = {};
    bf16x8 ones;
    #pragma unroll
    for (int i = 0; i < 8; i++) ones[i] = (short)0x3f80;   // bf16 1.0

    auto stage_load = [&](int j0, uint4& v0, uint4& v1) {
        const uint4* s = (const uint4*)(gH + (size_t)sr * NN + j0 + sc);
        v0 = s[0]; v1 = s[1];
    };
    auto stage_write = [&](int buf, uint4 v0, uint4 v1) {
        *(uint4*)(&hbh[buf][sr * SP + sc]) = v0;
        *(uint4*)(&hbh[buf][sr * SP + sc + 8]) = v1;
    };
    auto fd_load = [&](int j0, float4* p) {
        p[0] = *(const float4*)(fdh + j0 + aq * 8);
        p[1] = *(const float4*)(fdh + j0 + aq * 8 + 4);
        p[2] = *(const float4*)(fdh + j0 + 32 + aq * 8);
        p[3] = *(const float4*)(fdh + j0 + 32 + aq * 8 + 4);
    };
    // 8 scores -> one bf16x8 B-fragment; masks are wave-uniform 64-bit lane masks
    auto mkfrag = [&](float4 p0, float4 p1, const unsigned long long* mk, int off) -> bf16x8 {
        unsigned eu[8];
        #pragma unroll
        for (int q = 0; q < 2; q++) {
            float4 pv = q ? p1 : p0;
            #pragma unroll
            for (int bq = 0; bq < 4; bq++) {
                float tv = Ai + f4c(pv, bq);
                float uv = __builtin_fmaf(LRELU_ALPHA, tv, Ci);
                float ev = __builtin_amdgcn_exp2f(fmaxf(tv, uv));
                unsigned r;
                asm("v_cndmask_b32 %0, 0, %1, %2"
                    : "=v"(r) : "v"(ev), "s"(mk[off + q * 4 + bq]));
                eu[q * 4 + bq] = r;
            }
        }
        union { unsigned u[4]; bf16x8 v; } pk;
        pk.u[0] = __builtin_amdgcn_perm(eu[1], eu[0], 0x07060302);
        pk.u[1] = __builtin_amdgcn_perm(eu[3], eu[2], 0x07060302);
        pk.u[2] = __builtin_amdgcn_perm(eu[5], eu[4], 0x07060302);
        pk.u[3] = __builtin_amdgcn_perm(eu[7], eu[6], 0x07060302);
        return pk.v;
    };

    bf16x8 Pc0, Pc1;
    {   // prologue: first tile of this block's j-chunk
        uint4 v0, v1; float4 pf[4];
        stage_load(jlo, v0, v1);
        fd_load(jlo, pf);
        unsigned long long mk[16];
        #pragma unroll
        for (int k = 0; k < 16; k++) mk[k] = mbase[(size_t)(jlo >> 6) * 16 + k];
        Pc0 = mkfrag(pf[0], pf[1], mk, 0);
        Pc1 = mkfrag(pf[2], pf[3], mk, 8);
        stage_write(0, v0, v1);
        __syncthreads();
    }

    for (int j0 = jlo; j0 < jlo + JCHUNK; j0 += 64) {
        int cur = (j0 >> 6) & 1;
        int jn = jlo + ((j0 + 64 - jlo) & (JCHUNK - 1));   // wraps on last iter; harmless
        uint4 v0, v1; float4 pf[4];
        stage_load(jn, v0, v1);          // issue next-tile loads early (T14)
        fd_load(jn, pf);
        unsigned long long mk[16];
        #pragma unroll
        for (int k = 0; k < 16; k++) mk[k] = mbase[(size_t)(jn >> 6) * 16 + k];

        // consume current tile: hp A-frags from LDS, P B-frags from registers
        #pragma unroll
        for (int k2 = 0; k2 < 2; k2++) {
            int ko = k2 * 32 + aq * 8;
            bf16x8 x0 = *(const bf16x8*)(&hbh[cur][(am)      * SP + ko]);
            bf16x8 x1 = *(const bf16x8*)(&hbh[cur][(am + 16) * SP + ko]);
            bf16x8 x2 = *(const bf16x8*)(&hbh[cur][(am + 32) * SP + ko]);
            bf16x8 x3 = *(const bf16x8*)(&hbh[cur][(am + 48) * SP + ko]);
            bf16x8 P = k2 ? Pc1 : Pc0;
            acc[0] = __builtin_amdgcn_mfma_f32_16x16x32_bf16(x0, P, acc[0], 0, 0, 0);
            acc[1] = __builtin_amdgcn_mfma_f32_16x16x32_bf16(x1, P, acc[1], 0, 0, 0);
            acc[2] = __builtin_amdgcn_mfma_f32_16x16x32_bf16(x2, P, acc[2], 0, 0, 0);
            acc[3] = __builtin_amdgcn_mfma_f32_16x16x32_bf16(x3, P, acc[3], 0, 0, 0);
            accl   = __builtin_amdgcn_mfma_f32_16x16x32_bf16(ones, P, accl, 0, 0, 0);
        }

        stage_write(cur ^ 1, v0, v1);    // write next hp tile (other buffer)
        Pc0 = mkfrag(pf[0], pf[1], mk, 0);
        Pc1 = mkfrag(pf[2], pf[3], mk, 8);
        __syncthreads();
    }

    // Epilogue: lane holds partial O[f = 16mf + 4aq + r][i = am]; rowsum in accl[0].
    int row = i0 + w * 16 + am;
    float* obase = oacc + (size_t)row * (HH * FF) + h * FF;
    #pragma unroll
    for (int mf = 0; mf < 4; mf++)
        #pragma unroll
        for (int r = 0; r < 4; r++)
            unsafeAtomicAdd(obase + mf * 16 + aq * 4 + r, acc[mf][r]);
    if (aq == 0) unsafeAtomicAdd(oli + (size_t)row * HH + h, accl[0]);
}

// ================= Kernel 4: combine — normalize + fallback + ELU =================
__global__ __launch_bounds__(256) void k_comb(const float* __restrict__ oacc,
                                              const float* __restrict__ oli,
                                              const float* __restrict__ hpsum,
                                              float* __restrict__ outp) {
    int gid = blockIdx.x * 256 + threadIdx.x;          // one float4 of the output
    const float invN = 1.0f / NN;
    float4 v = ((const float4*)oacc)[gid];
    int rh = gid >> 4;                                  // [row][h]
    int h = rh & (HH - 1);
    int f0 = (gid & 15) * 4;
    float li = oli[rh];
    float4 o;
    if (li > 0.f) {
        float rl = 1.f / li;
        o.x = v.x * rl; o.y = v.y * rl; o.z = v.z * rl; o.w = v.w * rl;
    } else {                                            // all-masked row fallback
        o.x = hpsum[h * FF + f0]     * invN; o.y = hpsum[h * FF + f0 + 1] * invN;
        o.z = hpsum[h * FF + f0 + 2] * invN; o.w = hpsum[h * FF + f0 + 3] * invN;
    }
    o.x = o.x > 0.f ? o.x : __expf(o.x) - 1.f;
    o.y = o.y > 0.f ? o.y : __expf(o.y) - 1.f;
    o.z = o.z > 0.f ? o.z : __expf(o.z) - 1.f;
    o.w = o.w > 0.f ? o.w : __expf(o.w) - 1.f;
    ((float4*)outp)[gid] = o;
}

extern "C" void kernel_launch(void* const* d_in, const int* in_sizes, int n_in,
                              void* d_out, int out_size, void* d_ws, size_t ws_size,
                              hipStream_t stream) {
    const float* hmat = (const float*)d_in[0];
    const int*   adj  = (const int*)d_in[1];
    const float* W    = (const float*)d_in[2];
    const float* a    = (const float*)d_in[3];
    float* out = (float*)d_out;

    char* ws = (char*)d_ws;
    unsigned short* hpT_hi = (unsigned short*)(ws);                 // 4 MB
    unsigned long long* adjm = (unsigned long long*)(ws + (4u << 20)); // 2 MB
    unsigned short* wt_hi  = (unsigned short*)(ws + (6u << 20));    // 512 KB
    unsigned short* wt_lo  = (unsigned short*)(ws + (6u << 20) + (512u << 10));
    float* fs    = (float*)(ws + (7u << 20));                       // 128 KB
    float* fd    = (float*)(ws + (7u << 20) + (128u << 10));        // 128 KB
    unsigned* mxkey = (unsigned*)(ws + (7u << 20) + (256u << 10));  // 64 B
    float* hpsum = (float*)(mxkey + 16);                            // 2 KB
    float* oacc  = (float*)(ws + (7u << 20) + (512u << 10));        // 8 MB  [row][h][f]
    float* oli   = oacc + (size_t)NN * HH * FF;                     // 128 KB [row][h]

    k_prep   <<<dim3(1609),                 256, 0, stream>>>(adj, W, adjm, wt_hi, wt_lo,
                                                              mxkey, hpsum, oacc);
    k_hp_mfma<<<dim3(64, 8),                256, 0, stream>>>(hmat, wt_hi, wt_lo, a,
                                                              hpT_hi, fs, fd, hpsum, mxkey);
    k_attn   <<<dim3(NN / 64, HH, JSPLIT),  256, 0, stream>>>(fs, fd, mxkey, adjm,
                                                              hpT_hi, oacc, oli);
    k_comb   <<<dim3(NN * HH * FF / 1024),  256, 0, stream>>>(oacc, oli, hpsum, out);
}

// Round 4
// 186.563 us; speedup vs baseline: 1.2971x; 1.2971x over previous
//
#include <hip/hip_runtime.h>

#define NN 4096
#define DD 512
#define HH 8
#define FF 64
#define LRELU_ALPHA 0.2f
#define SP 72   // LDS row stride in bf16 elems
#define JSPLIT 2
#define JCHUNK (NN / JSPLIT)

typedef __attribute__((ext_vector_type(8))) short bf16x8;
typedef __attribute__((ext_vector_type(4))) float f32x4;

__device__ __forceinline__ float f4c(const float4& v, int k) {
    return k == 0 ? v.x : (k == 1 ? v.y : (k == 2 ? v.z : v.w));
}
__device__ __forceinline__ void f4s(float4& v, int k, float x) {
    if (k == 0) v.x = x; else if (k == 1) v.y = x; else if (k == 2) v.z = x; else v.w = x;
}
__device__ __forceinline__ unsigned short f2bf(float x) {   // RNE float->bf16
    unsigned u = __float_as_uint(x);
    return (unsigned short)((u + 0x7fffu + ((u >> 16) & 1u)) >> 16);
}
__device__ __forceinline__ float bf2f(unsigned short h) {
    return __uint_as_float(((unsigned)h) << 16);
}
// monotone float<->uint key for atomicMax on arbitrary-sign floats
__device__ __forceinline__ unsigned fkey(float x) {
    unsigned u = __float_as_uint(x);
    return (u & 0x80000000u) ? ~u : (u | 0x80000000u);
}
__device__ __forceinline__ float funkey(unsigned k) {
    unsigned u = (k & 0x80000000u) ? (k ^ 0x80000000u) : ~k;
    return __uint_as_float(u);
}

// ================= Kernel 1: fused prep =================
// [0,1024)     : adjacency -> lane-indexed 64-bit MFMA masks adjm[g][t][16]
//                bit l of adjm[g][t][k2*8+e] = adj[16g + (l&15)][64t + 32k2 + 8*(l>>4) + e]
// [1024,1088)  : split+transpose W -> wt_hi/wt_lo [h][f][d]
// 1088         : zero mxkey + hpsum
__global__ __launch_bounds__(256) void k_prep(const int* __restrict__ adj,
                                              const float* __restrict__ W,
                                              unsigned long long* __restrict__ adjm,
                                              unsigned short* __restrict__ wt_hi,
                                              unsigned short* __restrict__ wt_lo,
                                              unsigned* __restrict__ mxkey,
                                              float* __restrict__ hpsum) {
    __shared__ unsigned long long shbuf[2080];   // 16640 B, aliased per branch
    int b = blockIdx.x, t = threadIdx.x;
    if (b < 1024) {
        int g = b >> 2, cq = b & 3;
        int r0 = g * 16;
        int lane = t & 63, wv = t >> 6;
        unsigned long long (*w64)[17] = (unsigned long long(*)[17])shbuf;
        // phase 1: coalesced row-pack of 16 rows x 1024 cols into LDS words
        for (int r = 0; r < 16; r++) {
            #pragma unroll
            for (int q = 0; q < 4; q++) {
                int col = cq * 1024 + q * 256 + t;
                unsigned long long m = __ballot(adj[(size_t)(r0 + r) * NN + col] > 0);
                if (lane == 0) w64[r][q * 4 + wv] = m;
            }
        }
        __syncthreads();
        // phase 2: transpose-repack into lane-indexed MFMA masks via ballot
        for (int tt = wv; tt < 16; tt += 4) {
            unsigned long long wbits = w64[lane & 15][tt];
            unsigned long long my = 0;
            #pragma unroll
            for (int k = 0; k < 16; k++) {
                int shv = 32 * (k >> 3) + 8 * (lane >> 4) + (k & 7);
                unsigned long long bal = __ballot((unsigned)((wbits >> shv) & 1ULL));
                if (lane == k) my = bal;
            }
            if (lane < 16)
                adjm[((size_t)g * 64 + cq * 16 + tt) * 16 + lane] = my;
        }
    } else if (b < 1088) {
        float (*tile)[65] = (float(*)[65])shbuf;
        int idx = b - 1024;
        int h = idx >> 3;
        int d0 = (idx & 7) * 64;
        #pragma unroll
        for (int kidx = 0; kidx < 4; kidx++) {
            int id = t + 256 * kidx;
            int dd = id >> 4, f4i = (id & 15) * 4;
            float4 v = *(const float4*)(W + ((size_t)(h * DD + d0 + dd)) * FF + f4i);
            tile[dd][f4i] = v.x; tile[dd][f4i + 1] = v.y;
            tile[dd][f4i + 2] = v.z; tile[dd][f4i + 3] = v.w;
        }
        __syncthreads();
        int f = t >> 2, c = (t & 3) * 16;
        union { unsigned short s[16]; uint4 v[2]; } hb, lb;
        #pragma unroll
        for (int q = 0; q < 16; q++) {
            float v = tile[c + q][f];
            unsigned short hi = f2bf(v);
            hb.s[q] = hi;
            lb.s[q] = f2bf(v - bf2f(hi));
        }
        uint4* dh = (uint4*)(wt_hi + ((size_t)h * FF + f) * DD + d0 + c);
        uint4* dl = (uint4*)(wt_lo + ((size_t)h * FF + f) * DD + d0 + c);
        dh[0] = hb.v[0]; dh[1] = hb.v[1];
        dl[0] = lb.v[0]; dl[1] = lb.v[1];
    } else {
        if (t < 16) mxkey[t] = 0u;
        hpsum[t] = 0.f;
        hpsum[t + 256] = 0.f;
    }
}

// ================= Kernel 2: hp GEMM (inline fp32->hi/lo split of h; MFMA 3-product) ========
// Emits hpT_hi, fs/fd (PRE-SCALED by LOG2E), maxfd atomic on scaled fd, hpsum column-sum.
__global__ __launch_bounds__(256) void k_hp_mfma(const float* __restrict__ hmat,
                                                 const unsigned short* __restrict__ whi,
                                                 const unsigned short* __restrict__ wlo,
                                                 const float* __restrict__ a,
                                                 unsigned short* __restrict__ hpT_hi,
                                                 float* __restrict__ fs,
                                                 float* __restrict__ fd,
                                                 float* __restrict__ hpsum,
                                                 unsigned* __restrict__ mxkey) {
    __shared__ char smem[4 * 64 * SP * 2];   // 36864 B
    unsigned short* ah = (unsigned short*)smem;
    unsigned short* al = ah + 64 * SP;
    unsigned short* bh = al + 64 * SP;
    unsigned short* bl = bh + 64 * SP;

    int t = threadIdx.x;
    int h = blockIdx.y;
    int n0 = blockIdx.x * 64;
    int lane = t & 63;
    int w = t >> 6;
    int R0 = (w >> 1) * 32, F0 = (w & 1) * 32;
    int am = lane & 15, aq = lane >> 4;
    int sr = t >> 2, sc = (t & 3) * 16;

    const float* gha = hmat + (size_t)(n0 + sr) * DD;
    const unsigned short* gbh = whi + ((size_t)h * FF + sr) * DD;
    const unsigned short* gbl = wlo + ((size_t)h * FF + sr) * DD;

    f32x4 acc[2][2] = {};
    for (int kk = 0; kk < DD; kk += 64) {
        {   // h: fp32 load + inline hi/lo split
            float4 p0 = *(const float4*)(gha + kk + sc);
            float4 p1 = *(const float4*)(gha + kk + sc + 4);
            float4 p2 = *(const float4*)(gha + kk + sc + 8);
            float4 p3 = *(const float4*)(gha + kk + sc + 12);
            union { unsigned short s[16]; uint4 v[2]; } hb, lb;
            #pragma unroll
            for (int q = 0; q < 16; q++) {
                float v = q < 4 ? f4c(p0, q) : q < 8 ? f4c(p1, q - 4)
                          : q < 12 ? f4c(p2, q - 8) : f4c(p3, q - 12);
                unsigned short hi = f2bf(v);
                hb.s[q] = hi;
                lb.s[q] = f2bf(v - bf2f(hi));
            }
            *(uint4*)(ah + sr * SP + sc) = hb.v[0]; *(uint4*)(ah + sr * SP + sc + 8) = hb.v[1];
            *(uint4*)(al + sr * SP + sc) = lb.v[0]; *(uint4*)(al + sr * SP + sc + 8) = lb.v[1];
        }
        {
            const uint4* s2 = (const uint4*)(gbh + kk + sc);
            const uint4* s3 = (const uint4*)(gbl + kk + sc);
            uint4 w0 = s2[0], w1 = s2[1], x0 = s3[0], x1 = s3[1];
            *(uint4*)(bh + sr * SP + sc) = w0; *(uint4*)(bh + sr * SP + sc + 8) = w1;
            *(uint4*)(bl + sr * SP + sc) = x0; *(uint4*)(bl + sr * SP + sc + 8) = x1;
        }
        __syncthreads();
        #pragma unroll
        for (int k2 = 0; k2 < 2; k2++) {
            int ko = k2 * 32 + aq * 8;
            bf16x8 a0h = *(const bf16x8*)(ah + (R0 + am) * SP + ko);
            bf16x8 a1h = *(const bf16x8*)(ah + (R0 + 16 + am) * SP + ko);
            bf16x8 a0l = *(const bf16x8*)(al + (R0 + am) * SP + ko);
            bf16x8 a1l = *(const bf16x8*)(al + (R0 + 16 + am) * SP + ko);
            bf16x8 b0h = *(const bf16x8*)(bh + (F0 + am) * SP + ko);
            bf16x8 b1h = *(const bf16x8*)(bh + (F0 + 16 + am) * SP + ko);
            bf16x8 b0l = *(const bf16x8*)(bl + (F0 + am) * SP + ko);
            bf16x8 b1l = *(const bf16x8*)(bl + (F0 + 16 + am) * SP + ko);
            acc[0][0] = __builtin_amdgcn_mfma_f32_16x16x32_bf16(a0h, b0h, acc[0][0], 0, 0, 0);
            acc[0][1] = __builtin_amdgcn_mfma_f32_16x16x32_bf16(a0h, b1h, acc[0][1], 0, 0, 0);
            acc[1][0] = __builtin_amdgcn_mfma_f32_16x16x32_bf16(a1h, b0h, acc[1][0], 0, 0, 0);
            acc[1][1] = __builtin_amdgcn_mfma_f32_16x16x32_bf16(a1h, b1h, acc[1][1], 0, 0, 0);
            acc[0][0] = __builtin_amdgcn_mfma_f32_16x16x32_bf16(a0h, b0l, acc[0][0], 0, 0, 0);
            acc[0][1] = __builtin_amdgcn_mfma_f32_16x16x32_bf16(a0h, b1l, acc[0][1], 0, 0, 0);
            acc[1][0] = __builtin_amdgcn_mfma_f32_16x16x32_bf16(a1h, b0l, acc[1][0], 0, 0, 0);
            acc[1][1] = __builtin_amdgcn_mfma_f32_16x16x32_bf16(a1h, b1l, acc[1][1], 0, 0, 0);
            acc[0][0] = __builtin_amdgcn_mfma_f32_16x16x32_bf16(a0l, b0h, acc[0][0], 0, 0, 0);
            acc[0][1] = __builtin_amdgcn_mfma_f32_16x16x32_bf16(a0l, b1h, acc[0][1], 0, 0, 0);
            acc[1][0] = __builtin_amdgcn_mfma_f32_16x16x32_bf16(a1l, b0h, acc[1][0], 0, 0, 0);
            acc[1][1] = __builtin_amdgcn_mfma_f32_16x16x32_bf16(a1l, b1h, acc[1][1], 0, 0, 0);
        }
        __syncthreads();
    }

    // Epilogue: pack hi/lo to LDS [f][n], store hi, fs/fd (scaled by LOG2E), maxfd, hpsum.
    unsigned* tt = (unsigned*)smem;
    float* rs = (float*)(smem + 17408);
    float* rd = rs + 256;
    float* ash = rd + 256;
    if (t < 128) ash[t] = a[h * 2 * FF + t];
    int col = lane & 15, rbase = (lane >> 4) * 4;
    #pragma unroll
    for (int m16 = 0; m16 < 2; m16++) {
        #pragma unroll
        for (int n16 = 0; n16 < 2; n16++) {
            #pragma unroll
            for (int r = 0; r < 4; r++) {
                int nl = R0 + m16 * 16 + rbase + r;
                int f = F0 + n16 * 16 + col;
                float v = acc[m16][n16][r];
                unsigned short hi = f2bf(v);
                unsigned short lo = f2bf(v - bf2f(hi));
                tt[f * 68 + nl] = (unsigned)hi | ((unsigned)lo << 16);
            }
        }
    }
    __syncthreads();
    {
        int f = t >> 2, c = (t & 3) * 16;
        union { unsigned short s[16]; uint4 v[2]; } hb;
        float csum = 0.f;
        #pragma unroll
        for (int q = 0; q < 16; q++) {
            unsigned u = tt[f * 68 + c + q];
            hb.s[q] = (unsigned short)(u & 0xffffu);
            csum += bf2f((unsigned short)(u & 0xffffu)) + bf2f((unsigned short)(u >> 16));
        }
        uint4* dh = (uint4*)(hpT_hi + ((size_t)h * FF + f) * NN + n0 + c);
        dh[0] = hb.v[0]; dh[1] = hb.v[1];
        csum += __shfl_xor(csum, 1);
        csum += __shfl_xor(csum, 2);
        if ((t & 3) == 0) unsafeAtomicAdd(hpsum + h * FF + f, csum);
    }
    {
        int n = t & 63, g = t >> 6;
        float fsp = 0.f, fdp = 0.f;
        #pragma unroll
        for (int q = 0; q < 16; q++) {
            int f = g * 16 + q;
            unsigned u = tt[f * 68 + n];
            float v = bf2f((unsigned short)(u & 0xffffu)) + bf2f((unsigned short)(u >> 16));
            fsp += v * ash[f];
            fdp += v * ash[64 + f];
        }
        rs[g * 64 + n] = fsp;
        rd[g * 64 + n] = fdp;
    }
    __syncthreads();
    if (t < 64) {
        const float LOG2E = 1.44269504f;
        float fdv = (rd[t] + rd[64 + t] + rd[128 + t] + rd[192 + t]) * LOG2E;
        fs[(size_t)h * NN + n0 + t] = (rs[t] + rs[64 + t] + rs[128 + t] + rs[192 + t]) * LOG2E;
        fd[(size_t)h * NN + n0 + t] = fdv;
        unsigned key = fkey(fdv);
        #pragma unroll
        for (int off = 32; off; off >>= 1) key = max(key, (unsigned)__shfl_xor((int)key, off));
        if (t == 0) atomicMax(mxkey + h, key);
    }
}

// ================= Kernel 3: attention — in-block j-split, 8 waves, LDS combine ============
// grid (NN/64, HH), 512 threads = 8 waves. Wave w: j-half h2 = w>>2 (2048 cols),
// row-group rg = w&3 (16 i-rows). Verified round-1 loop body per wave; staging covers
// TWO 64-j tiles per iteration (one per half, 512 threads). Cross-half combine in LDS.
// 16 waves/CU (2 blocks x 8), no global atomics.
__global__ __launch_bounds__(512) void k_attn(const float* __restrict__ fs,
                                              const float* __restrict__ fd,
                                              const unsigned* __restrict__ mxkey,
                                              const unsigned long long* __restrict__ adjm,
                                              const unsigned short* __restrict__ hpT_hi,
                                              const float* __restrict__ hpsum,
                                              float* __restrict__ outp) {
    __shared__ unsigned short hbh[2][2][64 * SP];   // [dbuf][j-half][f*SP+j] = 36864 B

    int t = threadIdx.x;
    int h = blockIdx.y;
    int i0 = blockIdx.x * 64;
    int lane = t & 63;
    int w = t >> 6;              // 0..7
    int h2 = w >> 2;             // j-half
    int rg = w & 3;              // row-group
    int am = lane & 15, aq = lane >> 4;
    int th = t >> 8;             // staging: which half's tile this thread fills
    int ts = t & 255;
    int sr = ts >> 2, sc = (ts & 3) * 16;

    // per-row constants (scaled domain): arg = max(tv, 0.2*tv + Ci), tv = Ai + fdL_j
    float mfdL = funkey(mxkey[h]);
    float fsv = fs[(size_t)h * NN + i0 + rg * 16 + am];
    float sL = fsv + mfdL;
    float mrL = fmaxf(sL, LRELU_ALPHA * sL);
    float Ai = fsv - mrL;
    float Ci = -0.8f * mrL;

    int rgu = __builtin_amdgcn_readfirstlane(rg);
    int h2u = __builtin_amdgcn_readfirstlane(h2);
    const unsigned long long* mbase = adjm + ((size_t)(blockIdx.x * 4 + rgu) * 64) * 16;
    const unsigned short* gH = hpT_hi + (size_t)h * FF * NN;
    const float* fdh = fd + (size_t)h * NN + (size_t)h2u * JCHUNK;   // wave's half

    f32x4 acc[4] = {};
    f32x4 accl = {};
    bf16x8 ones;
    #pragma unroll
    for (int i = 0; i < 8; i++) ones[i] = (short)0x3f80;   // bf16 1.0

    auto stage_load = [&](int j0, uint4& v0, uint4& v1) {   // j0 relative to half
        const uint4* s = (const uint4*)(gH + (size_t)sr * NN + th * JCHUNK + j0 + sc);
        v0 = s[0]; v1 = s[1];
    };
    auto stage_write = [&](int buf, uint4 v0, uint4 v1) {
        *(uint4*)(&hbh[buf][th][sr * SP + sc]) = v0;
        *(uint4*)(&hbh[buf][th][sr * SP + sc + 8]) = v1;
    };
    auto fd_load = [&](int j0, float4* p) {
        p[0] = *(const float4*)(fdh + j0 + aq * 8);
        p[1] = *(const float4*)(fdh + j0 + aq * 8 + 4);
        p[2] = *(const float4*)(fdh + j0 + 32 + aq * 8);
        p[3] = *(const float4*)(fdh + j0 + 32 + aq * 8 + 4);
    };
    // 8 scores -> one bf16x8 B-fragment; masks are wave-uniform 64-bit lane masks
    auto mkfrag = [&](float4 p0, float4 p1, const unsigned long long* mk, int off) -> bf16x8 {
        unsigned eu[8];
        #pragma unroll
        for (int q = 0; q < 2; q++) {
            float4 pv = q ? p1 : p0;
            #pragma unroll
            for (int bq = 0; bq < 4; bq++) {
                float tv = Ai + f4c(pv, bq);
                float uv = __builtin_fmaf(LRELU_ALPHA, tv, Ci);
                float ev = __builtin_amdgcn_exp2f(fmaxf(tv, uv));
                unsigned r;
                asm("v_cndmask_b32 %0, 0, %1, %2"
                    : "=v"(r) : "v"(ev), "s"(mk[off + q * 4 + bq]));
                eu[q * 4 + bq] = r;
            }
        }
        union { unsigned u[4]; bf16x8 v; } pk;
        pk.u[0] = __builtin_amdgcn_perm(eu[1], eu[0], 0x07060302);
        pk.u[1] = __builtin_amdgcn_perm(eu[3], eu[2], 0x07060302);
        pk.u[2] = __builtin_amdgcn_perm(eu[5], eu[4], 0x07060302);
        pk.u[3] = __builtin_amdgcn_perm(eu[7], eu[6], 0x07060302);
        return pk.v;
    };

    bf16x8 Pc0, Pc1;
    {   // prologue: tile 0 of each half
        uint4 v0, v1; float4 pf[4];
        stage_load(0, v0, v1);
        fd_load(0, pf);
        unsigned long long mk[16];
        #pragma unroll
        for (int k = 0; k < 16; k++) mk[k] = mbase[(size_t)(h2u * 32) * 16 + k];
        Pc0 = mkfrag(pf[0], pf[1], mk, 0);
        Pc1 = mkfrag(pf[2], pf[3], mk, 8);
        stage_write(0, v0, v1);
        __syncthreads();
    }

    for (int j0 = 0; j0 < JCHUNK; j0 += 64) {
        int cur = (j0 >> 6) & 1;
        int jn = (j0 + 64) & (JCHUNK - 1);   // wraps on last iter; produce is harmless then
        uint4 v0, v1; float4 pf[4];
        stage_load(jn, v0, v1);              // issue next-tile loads early (T14)
        fd_load(jn, pf);
        unsigned long long mk[16];
        #pragma unroll
        for (int k = 0; k < 16; k++) mk[k] = mbase[(size_t)(h2u * 32 + (jn >> 6)) * 16 + k];

        // consume current tile of this wave's half: hp A-frags from LDS, P from registers
        #pragma unroll
        for (int k2 = 0; k2 < 2; k2++) {
            int ko = k2 * 32 + aq * 8;
            bf16x8 x0 = *(const bf16x8*)(&hbh[cur][h2][(am)      * SP + ko]);
            bf16x8 x1 = *(const bf16x8*)(&hbh[cur][h2][(am + 16) * SP + ko]);
            bf16x8 x2 = *(const bf16x8*)(&hbh[cur][h2][(am + 32) * SP + ko]);
            bf16x8 x3 = *(const bf16x8*)(&hbh[cur][h2][(am + 48) * SP + ko]);
            bf16x8 P = k2 ? Pc1 : Pc0;
            acc[0] = __builtin_amdgcn_mfma_f32_16x16x32_bf16(x0, P, acc[0], 0, 0, 0);
            acc[1] = __builtin_amdgcn_mfma_f32_16x16x32_bf16(x1, P, acc[1], 0, 0, 0);
            acc[2] = __builtin_amdgcn_mfma_f32_16x16x32_bf16(x2, P, acc[2], 0, 0, 0);
            acc[3] = __builtin_amdgcn_mfma_f32_16x16x32_bf16(x3, P, acc[3], 0, 0, 0);
            accl   = __builtin_amdgcn_mfma_f32_16x16x32_bf16(ones, P, accl, 0, 0, 0);
        }

        stage_write(cur ^ 1, v0, v1);        // write next hp tile (other buffer)
        Pc0 = mkfrag(pf[0], pf[1], mk, 0);
        Pc1 = mkfrag(pf[2], pf[3], mk, 8);
        __syncthreads();
    }

    // Cross-half combine in LDS (reuse staging buffer), then normalize + ELU + store.
    float* cb = (float*)hbh;                 // 4096 + 256 floats = 17.4 KB
    if (h2 == 1) {
        #pragma unroll
        for (int mf = 0; mf < 4; mf++)
            *(f32x4*)&cb[((rg * 4 + mf) * 64 + lane) * 4] = acc[mf];
        cb[4096 + rg * 64 + lane] = accl[0];
    }
    __syncthreads();
    if (h2 == 0) {
        #pragma unroll
        for (int mf = 0; mf < 4; mf++) {
            f32x4 o = *(const f32x4*)&cb[((rg * 4 + mf) * 64 + lane) * 4];
            acc[mf] += o;
        }
        float li = accl[0] + cb[4096 + rg * 64 + lane];
        const float invN = 1.0f / NN;
        float rl = 1.f / li;
        int row = i0 + rg * 16 + am;
        float* orow = outp + (size_t)row * (HH * FF) + h * FF;
        #pragma unroll
        for (int mf = 0; mf < 4; mf++) {
            float4 ov;
            #pragma unroll
            for (int r = 0; r < 4; r++) {
                int f = mf * 16 + aq * 4 + r;
                float v;
                if (li > 0.f) v = acc[mf][r] * rl;
                else          v = hpsum[h * FF + f] * invN;   // all-masked row fallback
                v = v > 0.f ? v : __expf(v) - 1.f;
                f4s(ov, r, v);
            }
            *(float4*)(orow + mf * 16 + aq * 4) = ov;
        }
    }
}

extern "C" void kernel_launch(void* const* d_in, const int* in_sizes, int n_in,
                              void* d_out, int out_size, void* d_ws, size_t ws_size,
                              hipStream_t stream) {
    const float* hmat = (const float*)d_in[0];
    const int*   adj  = (const int*)d_in[1];
    const float* W    = (const float*)d_in[2];
    const float* a    = (const float*)d_in[3];
    float* out = (float*)d_out;

    char* ws = (char*)d_ws;
    unsigned short* hpT_hi = (unsigned short*)(ws);                 // 4 MB
    unsigned long long* adjm = (unsigned long long*)(ws + (4u << 20)); // 2 MB
    unsigned short* wt_hi  = (unsigned short*)(ws + (6u << 20));    // 512 KB
    unsigned short* wt_lo  = (unsigned short*)(ws + (6u << 20) + (512u << 10));
    float* fs    = (float*)(ws + (7u << 20));                       // 128 KB
    float* fd    = (float*)(ws + (7u << 20) + (128u << 10));        // 128 KB
    unsigned* mxkey = (unsigned*)(ws + (7u << 20) + (256u << 10));  // 64 B
    float* hpsum = (float*)(mxkey + 16);                            // 2 KB

    k_prep   <<<dim3(1089),          256, 0, stream>>>(adj, W, adjm, wt_hi, wt_lo,
                                                       mxkey, hpsum);
    k_hp_mfma<<<dim3(64, 8),         256, 0, stream>>>(hmat, wt_hi, wt_lo, a,
                                                       hpT_hi, fs, fd, hpsum, mxkey);
    k_attn   <<<dim3(NN / 64, HH),   512, 0, stream>>>(fs, fd, mxkey, adjm,
                                                       hpT_hi, hpsum, out);
}